// Round 18
// baseline (380.919 us; speedup 1.0000x reference)
//
#include <hip/hip_runtime.h>
#include <math.h>

#define N_NODES 50000
#define N_EDGES 800000
#define IN_F 768
#define HID 128
#define CLS 40
#define CLSP 48
#define CSTRIDE 64   // padded row stride (shorts) for hc
#define EPS 1e-5f
#define LNS2 132     // f32 LDS stride for gemm23 tile
#define BK1 64       // K-step for staged GEMM1
#define NSH 8        // degree histogram shadows

typedef __attribute__((ext_vector_type(8))) short short8;
typedef __attribute__((ext_vector_type(4))) float f32x4;

__device__ inline unsigned short f2bf(float f) {
    union { float f; unsigned u; } x;
    x.f = f;
    unsigned u = x.u;
    return (unsigned short)((u + 0x7FFF + ((u >> 16) & 1)) >> 16);
}

__device__ inline float bf2f(unsigned short u) {
    union { unsigned u; float f; } x;
    x.u = ((unsigned)u) << 16;
    return x.f;
}

__device__ inline unsigned pack2bf(float a, float b) {
    return (unsigned)f2bf(a) | ((unsigned)f2bf(b) << 16);
}

__device__ inline void acc8(float* a, uint4 u) {
    a[0] += bf2f((unsigned short)(u.x & 0xFFFF));
    a[1] += bf2f((unsigned short)(u.x >> 16));
    a[2] += bf2f((unsigned short)(u.y & 0xFFFF));
    a[3] += bf2f((unsigned short)(u.y >> 16));
    a[4] += bf2f((unsigned short)(u.z & 0xFFFF));
    a[5] += bf2f((unsigned short)(u.z >> 16));
    a[6] += bf2f((unsigned short)(u.w & 0xFFFF));
    a[7] += bf2f((unsigned short)(u.w >> 16));
}

__device__ inline void acc4(float* a, uint2 u) {
    a[0] += bf2f((unsigned short)(u.x & 0xFFFF));
    a[1] += bf2f((unsigned short)(u.x >> 16));
    a[2] += bf2f((unsigned short)(u.y & 0xFFFF));
    a[3] += bf2f((unsigned short)(u.y >> 16));
}

// ---------------- fused: degree atomics + feat cvt/stats + weight prep ----------------
// Blocks [0, 6250): 1:1 interleave of per-edge atomics (even) and 16-lane cvtstat (odd).
// Blocks [6250, 6250+NB_CVT+32): weight transposes/convert + u,v column sums (tail,
// independent of everything — rides free while atomic/cvt blocks drain).

__global__ void k_deg_cvt(const int* __restrict__ src, const int* __restrict__ dst,
                          int* __restrict__ deg_out8, int* __restrict__ deg_in8,
                          const float* __restrict__ feat, unsigned short* __restrict__ Abf,
                          float* __restrict__ mu_o, float* __restrict__ rstd_o,
                          const float* __restrict__ W0, const float* __restrict__ W1,
                          const float* __restrict__ W2, const float* __restrict__ g_in,
                          const float* __restrict__ b_in,
                          unsigned short* __restrict__ Wg, unsigned short* __restrict__ Wt1,
                          unsigned short* __restrict__ Wt2,
                          float* __restrict__ u, float* __restrict__ v) {
    const int NB_E = (N_EDGES + 255) / 256;       // 3125
    const int NB_G16 = (N_NODES * 16 + 255) / 256; // 3125
    const int MAIN = NB_E + NB_G16;                // 6250
    const int S1 = HID * HID;
    const int S2 = S1 + HID * CLSP;
    const int S3 = S2 + IN_F * HID;
    const int NB_CVT = (S3 + 255) / 256;           // 472

    if ((int)blockIdx.x < MAIN) {
        int half = (int)blockIdx.x >> 1;
        if ((blockIdx.x & 1) == 0) {
            int e = half * 256 + (int)threadIdx.x;
            if (e < N_EDGES) {
                int sh = half & (NSH - 1);
                atomicAdd(&deg_out8[(size_t)sh * N_NODES + src[e]], 1);
                atomicAdd(&deg_in8[(size_t)sh * N_NODES + dst[e]], 1);
            }
            return;
        }
        // cvtstat: 16 lanes per row
        int grp = (half * 256 + (int)threadIdx.x) >> 4;
        int gl = threadIdx.x & 15;
        if (grp >= N_NODES) return;
        const float4* x4 = (const float4*)(feat + (size_t)grp * IN_F);
        float4 vv[12];
#pragma unroll
        for (int j = 0; j < 12; j++) vv[j] = x4[gl + 16 * j];
        float s = 0.f, q = 0.f;
#pragma unroll
        for (int j = 0; j < 12; j++) {
            float4 tv = vv[j];
            s += tv.x + tv.y + tv.z + tv.w;
            q += tv.x * tv.x + tv.y * tv.y + tv.z * tv.z + tv.w * tv.w;
        }
#pragma unroll
        for (int m = 1; m < 16; m <<= 1) {
            s += __shfl_xor(s, m);
            q += __shfl_xor(q, m);
        }
        float mu = s * (1.f / (float)IN_F);
        float var = q * (1.f / (float)IN_F) - mu * mu;
        float rstd = rsqrtf(var + EPS);
        ushort4* orow = (ushort4*)(Abf + (size_t)grp * IN_F);
#pragma unroll
        for (int j = 0; j < 12; j++) {
            ushort4 o;
            o.x = f2bf(vv[j].x); o.y = f2bf(vv[j].y);
            o.z = f2bf(vv[j].z); o.w = f2bf(vv[j].w);
            orow[gl + 16 * j] = o;
        }
        if (gl == 0) {
            mu_o[grp] = mu;
            rstd_o[grp] = rstd;
        }
        return;
    }
    // ---- weight prep tail ----
    int cb = (int)blockIdx.x - MAIN;
    if (cb < NB_CVT) {
        int idx = cb * 256 + threadIdx.x;
        if (idx < S1) {
            int c = idx / HID, k = idx % HID;
            Wt1[idx] = f2bf(W1[(size_t)k * HID + c]);
        } else if (idx < S2) {
            int j = idx - S1;
            int c = j / HID, k = j % HID;
            Wt2[j] = (c < CLS) ? f2bf(W2[(size_t)k * CLS + c]) : (unsigned short)0;
        } else if (idx < S3) {
            int j = idx - S2;
            int c = j / IN_F, k = j % IN_F;
            Wg[j] = f2bf(g_in[k] * W0[(size_t)k * HID + c]);
        }
    } else {
        int wvid = (cb - NB_CVT) * 4 + (threadIdx.x >> 6);
        int lane = threadIdx.x & 63;
        if (wvid < HID) {
            float us = 0.f, vs = 0.f;
#pragma unroll
            for (int i = 0; i < 12; i++) {
                int k = lane + 64 * i;
                float w0 = W0[(size_t)k * HID + wvid];
                us += bf2f(f2bf(g_in[k] * w0));  // match bf16-rounded Wg exactly
                vs += b_in[k] * w0;
            }
#pragma unroll
            for (int m = 1; m < 64; m <<= 1) {
                us += __shfl_xor(us, m);
                vs += __shfl_xor(vs, m);
            }
            if (lane == 0) { u[wvid] = us; v[wvid] = vs; }
        }
    }
}

// ---------------- segment offsets (sums 8 shadows) ----------------

__global__ void k_off(const int* __restrict__ deg_in8, const int* __restrict__ deg_out8,
                      int* __restrict__ deg_in_s, int* __restrict__ start,
                      float* __restrict__ do_is, float* __restrict__ di_is,
                      int* __restrict__ counter) {
    int i = blockIdx.x * 256 + threadIdx.x;
    int lane = threadIdx.x & 63;
    int d = 0, dout = 0;
    if (i < N_NODES) {
#pragma unroll
        for (int sh = 0; sh < NSH; sh++) {
            d += deg_in8[(size_t)sh * N_NODES + i];
            dout += deg_out8[(size_t)sh * N_NODES + i];
        }
    }
    int pre = d;
#pragma unroll
    for (int m = 1; m < 64; m <<= 1) {
        int vv = __shfl_up(pre, m);
        if (lane >= m) pre += vv;
    }
    int total = __shfl(pre, 63);
    int base = 0;
    if (lane == 63) base = atomicAdd(counter, total);
    base = __shfl(base, 63);
    if (i < N_NODES) {
        deg_in_s[i] = d;
        start[i] = base + pre - d;
        di_is[i] = rsqrtf((float)max(d, 1));
        do_is[i] = rsqrtf((float)max(dout, 1));
    }
}

// ---------------- fused: CSR fill (int4 edges) + GEMM1 staged ----------------

__global__ __launch_bounds__(256) void k_fill_gemm1(
        const int4* __restrict__ src4, const int4* __restrict__ dst4,
        const int* __restrict__ start, int* __restrict__ cnt, int* __restrict__ col,
        const unsigned short* __restrict__ Abf, const unsigned short* __restrict__ Wg,
        const float* __restrict__ mu, const float* __restrict__ rstd,
        const float* __restrict__ u, const float* __restrict__ v,
        const float* __restrict__ do_is, unsigned short* __restrict__ out) {
    __shared__ unsigned short As[2][8][64][8];  // 2 x 8 KB (gemm path only)
    if (blockIdx.x & 1) {
        // ---- CSR fill, 4 edges per thread ----
        int half = (int)blockIdx.x >> 1;
        int idx4 = half * 256 + (int)threadIdx.x;
        if (idx4 < N_EDGES / 4) {
            int4 s4 = src4[idx4];
            int4 d4 = dst4[idx4];
            int p0 = start[d4.x] + atomicAdd(&cnt[d4.x], 1);
            col[p0] = s4.x;
            int p1 = start[d4.y] + atomicAdd(&cnt[d4.y], 1);
            col[p1] = s4.y;
            int p2 = start[d4.z] + atomicAdd(&cnt[d4.z], 1);
            col[p2] = s4.z;
            int p3 = start[d4.w] + atomicAdd(&cnt[d4.w], 1);
            col[p3] = s4.w;
        }
        return;
    }
    // ---- GEMM1 staged ----
    int bid = (int)blockIdx.x >> 1;
    int t = threadIdx.x;
    int w = t >> 6, l = t & 63;
    int r0 = bid * 64;
    int c0 = w * 32;
    int lrow = l & 15, lk8 = l >> 4;

    const unsigned short* srow = Abf + (size_t)(r0 + l) * IN_F;  // per-lane source row

    const short8* bp0 = (const short8*)(Wg + (size_t)(c0 + lrow) * IN_F);
    const short8* bp1 = (const short8*)(Wg + (size_t)(c0 + 16 + lrow) * IN_F);

    f32x4 acc[4][2] = {};

#define STAGE1(bsel, s)                                                          \
    {                                                                            \
        _Pragma("unroll")                                                        \
        for (int i = 0; i < 2; i++) {                                            \
            int k8 = w * 2 + i;                                                  \
            __builtin_amdgcn_global_load_lds(                                    \
                (const __attribute__((address_space(1))) void*)(srow + (s)*BK1 + k8 * 8), \
                (__attribute__((address_space(3))) void*)(&As[bsel][k8][0][0]),  \
                16, 0, 0);                                                       \
        }                                                                        \
    }

    STAGE1(0, 0);
    __syncthreads();

#pragma unroll 1
    for (int s = 0; s < IN_F / BK1; s++) {
        int cur = s & 1;
        if (s + 1 < IN_F / BK1) STAGE1(cur ^ 1, s + 1);
#pragma unroll
        for (int j = 0; j < 2; j++) {
            short8 b0 = bp0[s * 8 + j * 4 + lk8];
            short8 b1 = bp1[s * 8 + j * 4 + lk8];
#pragma unroll
            for (int m = 0; m < 4; m++) {
                short8 av = *(const short8*)(&As[cur][j * 4 + lk8][m * 16 + lrow][0]);
                acc[m][0] = __builtin_amdgcn_mfma_f32_16x16x32_bf16(av, b0, acc[m][0], 0, 0, 0);
                acc[m][1] = __builtin_amdgcn_mfma_f32_16x16x32_bf16(av, b1, acc[m][1], 0, 0, 0);
            }
        }
        __syncthreads();
    }

    float u0 = u[c0 + lrow], v0 = v[c0 + lrow];
    float u1 = u[c0 + 16 + lrow], v1 = v[c0 + 16 + lrow];
#pragma unroll
    for (int m = 0; m < 4; m++) {
#pragma unroll
        for (int jj = 0; jj < 4; jj++) {
            int orow = r0 + m * 16 + lk8 * 4 + jj;
            if (orow < N_NODES) {
                float mur = mu[orow], rsr = rstd[orow], dor = do_is[orow];
                out[(size_t)orow * HID + c0 + lrow] =
                    f2bf((rsr * (acc[m][0][jj] - mur * u0) + v0) * dor);
                out[(size_t)orow * HID + c0 + 16 + lrow] =
                    f2bf((rsr * (acc[m][1][jj] - mur * u1) + v1) * dor);
            }
        }
    }
}

// ---------------- GEMM2 + LN + ReLU + GEMM3 fused ----------------

__global__ void k_gemm23(const unsigned short* __restrict__ A,
                         const unsigned short* __restrict__ Wt1,
                         const unsigned short* __restrict__ Wt2,
                         const float* __restrict__ di_is, const float* __restrict__ do_is,
                         const float* __restrict__ g, const float* __restrict__ b,
                         unsigned short* __restrict__ hc) {
    __shared__ float tile[64 * LNS2];  // 33.8 KB
    int t = threadIdx.x;
    int w = t >> 6, l = t & 63;
    int r0 = blockIdx.x * 64;
    int c0 = w * 32;
    int lrow = l & 15, lk8 = l >> 4;

    // --- GEMM2 ---
    const short8* ap[4];
#pragma unroll
    for (int m = 0; m < 4; m++) {
        int row = r0 + m * 16 + lrow;
        if (row > N_NODES - 1) row = N_NODES - 1;
        ap[m] = (const short8*)(A + (size_t)row * HID) + lk8;
    }
    const short8* bp[2];
#pragma unroll
    for (int n = 0; n < 2; n++) {
        bp[n] = (const short8*)(Wt1 + (size_t)(c0 + n * 16 + lrow) * HID) + lk8;
    }
    f32x4 acc[4][2] = {};
#pragma unroll
    for (int k0 = 0; k0 < HID / 8; k0 += 4) {
        short8 bv0 = bp[0][k0];
        short8 bv1 = bp[1][k0];
#pragma unroll
        for (int m = 0; m < 4; m++) {
            short8 av = ap[m][k0];
            acc[m][0] = __builtin_amdgcn_mfma_f32_16x16x32_bf16(av, bv0, acc[m][0], 0, 0, 0);
            acc[m][1] = __builtin_amdgcn_mfma_f32_16x16x32_bf16(av, bv1, acc[m][1], 0, 0, 0);
        }
    }
#pragma unroll
    for (int m = 0; m < 4; m++) {
#pragma unroll
        for (int j = 0; j < 4; j++) {
            int rl = m * 16 + lk8 * 4 + j;
            int grow = r0 + rl;
            float sc = di_is[(grow < N_NODES) ? grow : (N_NODES - 1)];
            tile[rl * LNS2 + c0 + lrow] = acc[m][0][j] * sc;
            tile[rl * LNS2 + c0 + 16 + lrow] = acc[m][1][j] * sc;
        }
    }
    __syncthreads();

    // --- LN + ReLU + x do_is (read-all -> barrier -> packed overwrite) ---
    int r = w * 16 + lrow;
    int qq = lk8;
    float s1 = 0.f, s2 = 0.f;
#pragma unroll
    for (int c = 0; c < 32; c++) {
        int cs = (c + qq * 8) & 31;
        float v = tile[r * LNS2 + qq * 32 + cs];
        s1 += v;
        s2 += v * v;
    }
    s1 += __shfl_xor(s1, 16); s2 += __shfl_xor(s2, 16);
    s1 += __shfl_xor(s1, 32); s2 += __shfl_xor(s2, 32);
    float mu = s1 * (1.f / 128.f);
    float var = s2 * (1.f / 128.f) - mu * mu;
    float rstd = rsqrtf(var + EPS);
    int grow = r0 + r;
    float sc = do_is[(grow < N_NODES) ? grow : (N_NODES - 1)];

    float vv0[16], vv1[16];
#pragma unroll
    for (int cc = 0; cc < 16; cc++) {
        vv0[cc] = tile[r * LNS2 + qq * 32 + 2 * cc];
        vv1[cc] = tile[r * LNS2 + qq * 32 + 2 * cc + 1];
    }
    __syncthreads();

    unsigned* tu = (unsigned*)tile;
    const float2* g2 = (const float2*)(g + qq * 32);
    const float2* b2v = (const float2*)(b + qq * 32);
#pragma unroll
    for (int cc = 0; cc < 16; cc++) {
        float2 gg = g2[cc];
        float2 bb = b2v[cc];
        float y0 = fmaxf((vv0[cc] - mu) * rstd * gg.x + bb.x, 0.f) * sc;
        float y1 = fmaxf((vv1[cc] - mu) * rstd * gg.y + bb.y, 0.f) * sc;
        tu[r * LNS2 + qq * 16 + cc] = pack2bf(y0, y1);
    }
    __syncthreads();

    // --- GEMM3 ---
    const short8* bp2[3];
#pragma unroll
    for (int n = 0; n < 3; n++) {
        bp2[n] = (const short8*)(Wt2 + (size_t)(n * 16 + lrow) * HID) + lk8;
    }
    f32x4 a3[3] = {};
#pragma unroll
    for (int kf = 0; kf < 4; kf++) {
        short8 av = *(const short8*)(&tu[(w * 16 + lrow) * LNS2 + kf * 16 + lk8 * 4]);
#pragma unroll
        for (int n = 0; n < 3; n++) {
            a3[n] = __builtin_amdgcn_mfma_f32_16x16x32_bf16(av, bp2[n][kf * 4], a3[n], 0, 0, 0);
        }
    }
#pragma unroll
    for (int n = 0; n < 3; n++) {
        int colw = n * 16 + lrow;
#pragma unroll
        for (int j = 0; j < 4; j++) {
            int orow = r0 + w * 16 + lk8 * 4 + j;
            if (orow < N_NODES) hc[(size_t)orow * CSTRIDE + colw] = f2bf(a3[n][j]);
        }
    }
}

// ---------------- agg + LN + ReLU (layer 0): 16 lanes/node, depth-2 pipelined gathers ----------------

__global__ void k_aggln(const unsigned short* __restrict__ h, const int* __restrict__ start,
                        const int* __restrict__ deg, const int* __restrict__ col,
                        const float* __restrict__ di_is, const float* __restrict__ do_is,
                        const float* __restrict__ g, const float* __restrict__ b,
                        unsigned* __restrict__ out) {
    int grp = (blockIdx.x * blockDim.x + threadIdx.x) >> 4;
    int gl = threadIdx.x & 15;
    if (grp >= N_NODES) return;
    int s0 = start[grp], e0 = s0 + deg[grp];
    const uint4* h4 = (const uint4*)h;  // row = 16 uint4
    float a[8] = {};
    int n8 = (e0 - s0) >> 3;
    uint4 u0[8], u1[8];
    if (n8 > 0) {
#pragma unroll
        for (int k = 0; k < 8; k++) u0[k] = h4[(size_t)col[s0 + k] * 16 + gl];
    }
    if (n8 > 1) {
#pragma unroll
        for (int k = 0; k < 8; k++) u1[k] = h4[(size_t)col[s0 + 8 + k] * 16 + gl];
    }
    int bq = 0;
    for (; bq + 1 < n8; bq += 2) {
#pragma unroll
        for (int k = 0; k < 8; k++) acc8(a, u0[k]);
        if (bq + 2 < n8) {
            int base = s0 + (bq + 2) * 8;
#pragma unroll
            for (int k = 0; k < 8; k++) u0[k] = h4[(size_t)col[base + k] * 16 + gl];
        }
#pragma unroll
        for (int k = 0; k < 8; k++) acc8(a, u1[k]);
        if (bq + 3 < n8) {
            int base = s0 + (bq + 3) * 8;
#pragma unroll
            for (int k = 0; k < 8; k++) u1[k] = h4[(size_t)col[base + k] * 16 + gl];
        }
    }
    if (bq < n8) {
#pragma unroll
        for (int k = 0; k < 8; k++) acc8(a, u0[k]);
    }
    for (int i = s0 + n8 * 8; i < e0; i++) acc8(a, h4[(size_t)col[i] * 16 + gl]);

    float di = di_is[grp];
#pragma unroll
    for (int j = 0; j < 8; j++) a[j] *= di;
    float s = 0.f, q = 0.f;
#pragma unroll
    for (int j = 0; j < 8; j++) { s += a[j]; q += a[j] * a[j]; }
#pragma unroll
    for (int m = 1; m < 16; m <<= 1) {
        s += __shfl_xor(s, m);
        q += __shfl_xor(q, m);
    }
    float mu = s * (1.f / 128.f);
    float var = q * (1.f / 128.f) - mu * mu;
    float rstd = rsqrtf(var + EPS);
    float sc = do_is[grp];
    const float4* g4 = (const float4*)(g + gl * 8);
    const float4* b4 = (const float4*)(b + gl * 8);
    float4 g0v = g4[0], g1v = g4[1];
    float4 b0v = b4[0], b1v = b4[1];
    uint4 o;
    o.x = pack2bf(fmaxf((a[0] - mu) * rstd * g0v.x + b0v.x, 0.f) * sc,
                  fmaxf((a[1] - mu) * rstd * g0v.y + b0v.y, 0.f) * sc);
    o.y = pack2bf(fmaxf((a[2] - mu) * rstd * g0v.z + b0v.z, 0.f) * sc,
                  fmaxf((a[3] - mu) * rstd * g0v.w + b0v.w, 0.f) * sc);
    o.z = pack2bf(fmaxf((a[4] - mu) * rstd * g1v.x + b1v.x, 0.f) * sc,
                  fmaxf((a[5] - mu) * rstd * g1v.y + b1v.y, 0.f) * sc);
    o.w = pack2bf(fmaxf((a[6] - mu) * rstd * g1v.z + b1v.z, 0.f) * sc,
                  fmaxf((a[7] - mu) * rstd * g1v.w + b1v.w, 0.f) * sc);
    ((uint4*)out)[(size_t)grp * 16 + gl] = o;
}

// ---------------- agg (layer 1): 16 lanes/node, depth-2 pipelined gathers ----------------

__global__ void k_agg128b(const unsigned short* __restrict__ h, const int* __restrict__ start,
                          const int* __restrict__ deg, const int* __restrict__ col,
                          unsigned* __restrict__ out) {
    int grp = (blockIdx.x * blockDim.x + threadIdx.x) >> 4;
    int gl = threadIdx.x & 15;
    if (grp >= N_NODES) return;
    int s0 = start[grp], e0 = s0 + deg[grp];
    const uint4* h4 = (const uint4*)h;
    float a[8] = {};
    int n8 = (e0 - s0) >> 3;
    uint4 u0[8], u1[8];
    if (n8 > 0) {
#pragma unroll
        for (int k = 0; k < 8; k++) u0[k] = h4[(size_t)col[s0 + k] * 16 + gl];
    }
    if (n8 > 1) {
#pragma unroll
        for (int k = 0; k < 8; k++) u1[k] = h4[(size_t)col[s0 + 8 + k] * 16 + gl];
    }
    int bq = 0;
    for (; bq + 1 < n8; bq += 2) {
#pragma unroll
        for (int k = 0; k < 8; k++) acc8(a, u0[k]);
        if (bq + 2 < n8) {
            int base = s0 + (bq + 2) * 8;
#pragma unroll
            for (int k = 0; k < 8; k++) u0[k] = h4[(size_t)col[base + k] * 16 + gl];
        }
#pragma unroll
        for (int k = 0; k < 8; k++) acc8(a, u1[k]);
        if (bq + 3 < n8) {
            int base = s0 + (bq + 3) * 8;
#pragma unroll
            for (int k = 0; k < 8; k++) u1[k] = h4[(size_t)col[base + k] * 16 + gl];
        }
    }
    if (bq < n8) {
#pragma unroll
        for (int k = 0; k < 8; k++) acc8(a, u0[k]);
    }
    for (int i = s0 + n8 * 8; i < e0; i++) acc8(a, h4[(size_t)col[i] * 16 + gl]);

    uint4 o;
    o.x = pack2bf(a[0], a[1]);
    o.y = pack2bf(a[2], a[3]);
    o.z = pack2bf(a[4], a[5]);
    o.w = pack2bf(a[6], a[7]);
    ((uint4*)out)[(size_t)grp * 16 + gl] = o;
}

// ---------------- agg (layer 2): 16 lanes/node, uint2 gathers on padded rows, idx prefetch ----------------

__global__ void k_agg40b(const unsigned short* __restrict__ h, const int* __restrict__ start,
                         const int* __restrict__ deg, const int* __restrict__ col,
                         const float* __restrict__ di_is, const float* __restrict__ b2,
                         float* __restrict__ out) {
    int grp = (blockIdx.x * blockDim.x + threadIdx.x) >> 4;
    int gl = threadIdx.x & 15;
    if (grp >= N_NODES) return;
    int s0 = start[grp], e0 = s0 + deg[grp];
    const uint2* h2 = (const uint2*)h;  // padded row = 16 uint2 (128 B)
    float a[4] = {};
    int n8 = (e0 - s0) >> 3;
    int idx[8];
    if (n8 > 0) {
#pragma unroll
        for (int k = 0; k < 8; k++) idx[k] = col[s0 + k];
    }
    for (int bq = 0; bq < n8; bq++) {
        uint2 u[8];
#pragma unroll
        for (int k = 0; k < 8; k++) u[k] = h2[(size_t)idx[k] * 16 + gl];
        if (bq + 1 < n8) {
            int base = s0 + (bq + 1) * 8;
#pragma unroll
            for (int k = 0; k < 8; k++) idx[k] = col[base + k];
        }
#pragma unroll
        for (int k = 0; k < 8; k++) acc4(a, u[k]);
    }
    for (int i = s0 + n8 * 8; i < e0; i++) acc4(a, h2[(size_t)col[i] * 16 + gl]);

    if (gl < CLS / 4) {  // lanes 0..9 cover the 40 real channels
        float di = di_is[grp];
        float4 bb = *(const float4*)(b2 + gl * 4);
        float4 o;
        o.x = a[0] * di + bb.x;
        o.y = a[1] * di + bb.y;
        o.z = a[2] * di + bb.z;
        o.w = a[3] * di + bb.w;
        *(float4*)(out + (size_t)grp * CLS + gl * 4) = o;
    }
}

// ---------------- launch ----------------

extern "C" void kernel_launch(void* const* d_in, const int* in_sizes, int n_in,
                              void* d_out, int out_size, void* d_ws, size_t ws_size,
                              hipStream_t stream) {
    (void)in_sizes; (void)n_in; (void)out_size; (void)ws_size;
    const float* feat = (const float*)d_in[0];
    const int*   src  = (const int*)d_in[1];
    const int*   dst  = (const int*)d_in[2];
    const float* W0   = (const float*)d_in[3];
    const float* W1   = (const float*)d_in[4];
    const float* W2   = (const float*)d_in[5];
    const float* b2   = (const float*)d_in[6];
    const float* g_in = (const float*)d_in[7];
    const float* b_in = (const float*)d_in[8];
    const float* g0   = (const float*)d_in[9];
    const float* b0   = (const float*)d_in[10];
    const float* g1   = (const float*)d_in[11];
    const float* b1   = (const float*)d_in[12];
    float* out = (float*)d_out;

    char* w = (char*)d_ws;
    size_t off = 0;
    auto take = [&](size_t bytes) -> void* {
        void* p = w + off;
        off += (bytes + 255) & ~(size_t)255;
        return p;
    };
    // zeroed region: deg_out8[8][N] | deg_in8[8][N] | cnt | counter
    const size_t SZ8N = ((size_t)NSH * N_NODES * 4 + 255) & ~(size_t)255;
    const size_t SZN = ((size_t)N_NODES * 4 + 255) & ~(size_t)255;
    char* zblk      = (char*)take(2 * SZ8N + SZN + 256);
    int*  deg_out8  = (int*)zblk;
    int*  deg_in8   = (int*)(zblk + SZ8N);
    int*  cnt       = (int*)(zblk + 2 * SZ8N);
    int*  counter   = (int*)(zblk + 2 * SZ8N + SZN);

    int*   deg_in_s  = (int*)take((size_t)N_NODES * 4);
    float* do_is     = (float*)take((size_t)N_NODES * 4);
    float* di_is     = (float*)take((size_t)N_NODES * 4);
    int*   start     = (int*)take((size_t)N_NODES * 4);
    int*   col       = (int*)take((size_t)N_EDGES * 4);
    float* mu        = (float*)take((size_t)N_NODES * 4);
    float* rstd      = (float*)take((size_t)N_NODES * 4);
    float* uvec      = (float*)take((size_t)HID * 4);
    float* vvec      = (float*)take((size_t)HID * 4);
    unsigned short* Abf = (unsigned short*)take((size_t)(N_NODES + 64) * IN_F * 2);
    unsigned short* Wg  = (unsigned short*)take((size_t)IN_F * HID * 2);
    unsigned short* Wt1 = (unsigned short*)take((size_t)HID * HID * 2);
    unsigned short* Wt2 = (unsigned short*)take((size_t)HID * CLSP * 2);
    unsigned short* h0  = (unsigned short*)take((size_t)N_NODES * HID * 2);
    unsigned short* h1  = (unsigned short*)take((size_t)N_NODES * HID * 2);
    unsigned short* hb  = (unsigned short*)take((size_t)N_NODES * HID * 2);
    unsigned short* hc  = (unsigned short*)take((size_t)N_NODES * CSTRIDE * 2);

    const int NB_N = (N_NODES + 255) / 256;
    const int NB_E = (N_EDGES + 255) / 256;           // 3125
    const int NB_E4 = (N_EDGES / 4 + 255) / 256;      // 782 (int4 edge blocks, fill)
    const int NB_M64 = (N_NODES + 63) / 64;           // 782
    const int NB_G16 = (N_NODES * 16 + 255) / 256;    // 3125 (16 lanes per node)
    const int S3 = HID * HID + HID * CLSP + IN_F * HID;  // 120832
    const int NB_CVT = (S3 + 255) / 256;                 // 472

    hipMemsetAsync(zblk, 0, 2 * SZ8N + SZN + 256, stream);

    // atomics + cvtstat (1:1) with weight-prep tail blocks
    k_deg_cvt<<<NB_E + NB_G16 + NB_CVT + 32, 256, 0, stream>>>(
        src, dst, deg_out8, deg_in8, feat, Abf, mu, rstd,
        W0, W1, W2, g_in, b_in, Wg, Wt1, Wt2, uvec, vvec);
    // offsets (sums shadows)
    k_off<<<NB_N, 256, 0, stream>>>(deg_in8, deg_out8, deg_in_s, start, do_is, di_is, counter);

    // fused: even blocks = GEMM1 (LN folded), odd blocks = CSR fill (int4 edges)
    k_fill_gemm1<<<NB_E4 + NB_M64, 256, 0, stream>>>((const int4*)src, (const int4*)dst,
                                                     start, cnt, col, Abf, Wg, mu, rstd,
                                                     uvec, vvec, do_is, h0);

    // Layer 0 epilogue: h1 = relu(LN(agg(h0)*di_is))*do_is
    k_aggln<<<NB_G16, 256, 0, stream>>>(h0, start, deg_in_s, col, di_is, do_is, g0, b0, (unsigned*)h1);

    // Layer 1+2a: hb = agg(h1) ; hc = (relu(LN((hb@W1)*di_is))*do_is) @ W2
    k_agg128b<<<NB_G16, 256, 0, stream>>>(h1, start, deg_in_s, col, (unsigned*)hb);
    k_gemm23<<<NB_M64, 256, 0, stream>>>(hb, Wt1, Wt2, di_is, do_is, g1, b1, hc);

    // Layer 2b: out = agg(hc)*di_is + b2
    k_agg40b<<<NB_G16, 256, 0, stream>>>(hc, start, deg_in_s, col, di_is, b2, out);
}

// Round 19
// 277.687 us; speedup vs baseline: 1.3718x; 1.3718x over previous
//
#include <hip/hip_runtime.h>
#include <math.h>

#define N_NODES 50000
#define N_EDGES 800000
#define IN_F 768
#define HID 128
#define CLS 40
#define CLSP 48
#define CSTRIDE 64   // padded row stride (shorts) for hc
#define EPS 1e-5f
#define LNS2 132     // f32 LDS stride for gemm23 tile
#define BK1 64       // K-step for staged GEMM1
#define NSH 8        // degree histogram shadows

typedef __attribute__((ext_vector_type(8))) short short8;
typedef __attribute__((ext_vector_type(4))) float f32x4;

__device__ inline unsigned short f2bf(float f) {
    union { float f; unsigned u; } x;
    x.f = f;
    unsigned u = x.u;
    return (unsigned short)((u + 0x7FFF + ((u >> 16) & 1)) >> 16);
}

__device__ inline float bf2f(unsigned short u) {
    union { unsigned u; float f; } x;
    x.u = ((unsigned)u) << 16;
    return x.f;
}

__device__ inline unsigned pack2bf(float a, float b) {
    return (unsigned)f2bf(a) | ((unsigned)f2bf(b) << 16);
}

__device__ inline void acc8(float* a, uint4 u) {
    a[0] += bf2f((unsigned short)(u.x & 0xFFFF));
    a[1] += bf2f((unsigned short)(u.x >> 16));
    a[2] += bf2f((unsigned short)(u.y & 0xFFFF));
    a[3] += bf2f((unsigned short)(u.y >> 16));
    a[4] += bf2f((unsigned short)(u.z & 0xFFFF));
    a[5] += bf2f((unsigned short)(u.z >> 16));
    a[6] += bf2f((unsigned short)(u.w & 0xFFFF));
    a[7] += bf2f((unsigned short)(u.w >> 16));
}

__device__ inline void acc4(float* a, uint2 u) {
    a[0] += bf2f((unsigned short)(u.x & 0xFFFF));
    a[1] += bf2f((unsigned short)(u.x >> 16));
    a[2] += bf2f((unsigned short)(u.y & 0xFFFF));
    a[3] += bf2f((unsigned short)(u.y >> 16));
}

// ---------------- fused: degree atomics + feat cvt/stats + weight prep ----------------
// Blocks [0, 6250): 1:1 interleave of per-edge atomics (even) and 16-lane cvtstat (odd).
// Blocks [6250, +NB_CVT+32): weight prep tail (independent; rides free while main drains).

__global__ void k_deg_cvt(const int* __restrict__ src, const int* __restrict__ dst,
                          int* __restrict__ deg_out8, int* __restrict__ deg_in8,
                          const float* __restrict__ feat, unsigned short* __restrict__ Abf,
                          float* __restrict__ mu_o, float* __restrict__ rstd_o,
                          const float* __restrict__ W0, const float* __restrict__ W1,
                          const float* __restrict__ W2, const float* __restrict__ g_in,
                          const float* __restrict__ b_in,
                          unsigned short* __restrict__ Wg, unsigned short* __restrict__ Wt1,
                          unsigned short* __restrict__ Wt2,
                          float* __restrict__ u, float* __restrict__ v) {
    const int NB_E = (N_EDGES + 255) / 256;        // 3125
    const int NB_G16 = (N_NODES * 16 + 255) / 256; // 3125
    const int MAIN = NB_E + NB_G16;                // 6250
    const int S1 = HID * HID;
    const int S2 = S1 + HID * CLSP;
    const int S3 = S2 + IN_F * HID;
    const int NB_CVT = (S3 + 255) / 256;           // 472

    if ((int)blockIdx.x < MAIN) {
        int half = (int)blockIdx.x >> 1;
        if ((blockIdx.x & 1) == 0) {
            int e = half * 256 + (int)threadIdx.x;
            if (e < N_EDGES) {
                int sh = half & (NSH - 1);
                atomicAdd(&deg_out8[(size_t)sh * N_NODES + src[e]], 1);
                atomicAdd(&deg_in8[(size_t)sh * N_NODES + dst[e]], 1);
            }
            return;
        }
        // cvtstat: 16 lanes per row
        int grp = (half * 256 + (int)threadIdx.x) >> 4;
        int gl = threadIdx.x & 15;
        if (grp >= N_NODES) return;
        const float4* x4 = (const float4*)(feat + (size_t)grp * IN_F);
        float4 vv[12];
#pragma unroll
        for (int j = 0; j < 12; j++) vv[j] = x4[gl + 16 * j];
        float s = 0.f, q = 0.f;
#pragma unroll
        for (int j = 0; j < 12; j++) {
            float4 tv = vv[j];
            s += tv.x + tv.y + tv.z + tv.w;
            q += tv.x * tv.x + tv.y * tv.y + tv.z * tv.z + tv.w * tv.w;
        }
#pragma unroll
        for (int m = 1; m < 16; m <<= 1) {
            s += __shfl_xor(s, m);
            q += __shfl_xor(q, m);
        }
        float mu = s * (1.f / (float)IN_F);
        float var = q * (1.f / (float)IN_F) - mu * mu;
        float rstd = rsqrtf(var + EPS);
        ushort4* orow = (ushort4*)(Abf + (size_t)grp * IN_F);
#pragma unroll
        for (int j = 0; j < 12; j++) {
            ushort4 o;
            o.x = f2bf(vv[j].x); o.y = f2bf(vv[j].y);
            o.z = f2bf(vv[j].z); o.w = f2bf(vv[j].w);
            orow[gl + 16 * j] = o;
        }
        if (gl == 0) {
            mu_o[grp] = mu;
            rstd_o[grp] = rstd;
        }
        return;
    }
    // ---- weight prep tail ----
    int cb = (int)blockIdx.x - MAIN;
    if (cb < NB_CVT) {
        int idx = cb * 256 + threadIdx.x;
        if (idx < S1) {
            int c = idx / HID, k = idx % HID;
            Wt1[idx] = f2bf(W1[(size_t)k * HID + c]);
        } else if (idx < S2) {
            int j = idx - S1;
            int c = j / HID, k = j % HID;
            Wt2[j] = (c < CLS) ? f2bf(W2[(size_t)k * CLS + c]) : (unsigned short)0;
        } else if (idx < S3) {
            int j = idx - S2;
            int c = j / IN_F, k = j % IN_F;
            Wg[j] = f2bf(g_in[k] * W0[(size_t)k * HID + c]);
        }
    } else {
        int wvid = (cb - NB_CVT) * 4 + (threadIdx.x >> 6);
        int lane = threadIdx.x & 63;
        if (wvid < HID) {
            float us = 0.f, vs = 0.f;
#pragma unroll
            for (int i = 0; i < 12; i++) {
                int k = lane + 64 * i;
                float w0 = W0[(size_t)k * HID + wvid];
                us += bf2f(f2bf(g_in[k] * w0));  // match bf16-rounded Wg exactly
                vs += b_in[k] * w0;
            }
#pragma unroll
            for (int m = 1; m < 64; m <<= 1) {
                us += __shfl_xor(us, m);
                vs += __shfl_xor(vs, m);
            }
            if (lane == 0) { u[wvid] = us; v[wvid] = vs; }
        }
    }
}

// ---------------- segment offsets (sums 8 shadows) ----------------

__global__ void k_off(const int* __restrict__ deg_in8, const int* __restrict__ deg_out8,
                      int* __restrict__ deg_in_s, int* __restrict__ start,
                      float* __restrict__ do_is, float* __restrict__ di_is,
                      int* __restrict__ counter) {
    int i = blockIdx.x * 256 + threadIdx.x;
    int lane = threadIdx.x & 63;
    int d = 0, dout = 0;
    if (i < N_NODES) {
#pragma unroll
        for (int sh = 0; sh < NSH; sh++) {
            d += deg_in8[(size_t)sh * N_NODES + i];
            dout += deg_out8[(size_t)sh * N_NODES + i];
        }
    }
    int pre = d;
#pragma unroll
    for (int m = 1; m < 64; m <<= 1) {
        int vv = __shfl_up(pre, m);
        if (lane >= m) pre += vv;
    }
    int total = __shfl(pre, 63);
    int base = 0;
    if (lane == 63) base = atomicAdd(counter, total);
    base = __shfl(base, 63);
    if (i < N_NODES) {
        deg_in_s[i] = d;
        start[i] = base + pre - d;
        di_is[i] = rsqrtf((float)max(d, 1));
        do_is[i] = rsqrtf((float)max(dout, 1));
    }
}

// ---------------- fused: CSR fill (int4 edges) + GEMM1 staged ----------------

__global__ __launch_bounds__(256) void k_fill_gemm1(
        const int4* __restrict__ src4, const int4* __restrict__ dst4,
        const int* __restrict__ start, int* __restrict__ cnt, int* __restrict__ col,
        const unsigned short* __restrict__ Abf, const unsigned short* __restrict__ Wg,
        const float* __restrict__ mu, const float* __restrict__ rstd,
        const float* __restrict__ u, const float* __restrict__ v,
        const float* __restrict__ do_is, unsigned short* __restrict__ out) {
    __shared__ unsigned short As[2][8][64][8];  // 2 x 8 KB (gemm path only)
    if (blockIdx.x & 1) {
        // ---- CSR fill, 4 edges per thread ----
        int half = (int)blockIdx.x >> 1;
        int idx4 = half * 256 + (int)threadIdx.x;
        if (idx4 < N_EDGES / 4) {
            int4 s4 = src4[idx4];
            int4 d4 = dst4[idx4];
            int p0 = start[d4.x] + atomicAdd(&cnt[d4.x], 1);
            col[p0] = s4.x;
            int p1 = start[d4.y] + atomicAdd(&cnt[d4.y], 1);
            col[p1] = s4.y;
            int p2 = start[d4.z] + atomicAdd(&cnt[d4.z], 1);
            col[p2] = s4.z;
            int p3 = start[d4.w] + atomicAdd(&cnt[d4.w], 1);
            col[p3] = s4.w;
        }
        return;
    }
    // ---- GEMM1 staged ----
    int bid = (int)blockIdx.x >> 1;
    int t = threadIdx.x;
    int w = t >> 6, l = t & 63;
    int r0 = bid * 64;
    int c0 = w * 32;
    int lrow = l & 15, lk8 = l >> 4;

    const unsigned short* srow = Abf + (size_t)(r0 + l) * IN_F;  // per-lane source row

    const short8* bp0 = (const short8*)(Wg + (size_t)(c0 + lrow) * IN_F);
    const short8* bp1 = (const short8*)(Wg + (size_t)(c0 + 16 + lrow) * IN_F);

    f32x4 acc[4][2] = {};

#define STAGE1(bsel, s)                                                          \
    {                                                                            \
        _Pragma("unroll")                                                        \
        for (int i = 0; i < 2; i++) {                                            \
            int k8 = w * 2 + i;                                                  \
            __builtin_amdgcn_global_load_lds(                                    \
                (const __attribute__((address_space(1))) void*)(srow + (s)*BK1 + k8 * 8), \
                (__attribute__((address_space(3))) void*)(&As[bsel][k8][0][0]),  \
                16, 0, 0);                                                       \
        }                                                                        \
    }

    STAGE1(0, 0);
    __syncthreads();

#pragma unroll 1
    for (int s = 0; s < IN_F / BK1; s++) {
        int cur = s & 1;
        if (s + 1 < IN_F / BK1) STAGE1(cur ^ 1, s + 1);
#pragma unroll
        for (int j = 0; j < 2; j++) {
            short8 b0 = bp0[s * 8 + j * 4 + lk8];
            short8 b1 = bp1[s * 8 + j * 4 + lk8];
#pragma unroll
            for (int m = 0; m < 4; m++) {
                short8 av = *(const short8*)(&As[cur][j * 4 + lk8][m * 16 + lrow][0]);
                acc[m][0] = __builtin_amdgcn_mfma_f32_16x16x32_bf16(av, b0, acc[m][0], 0, 0, 0);
                acc[m][1] = __builtin_amdgcn_mfma_f32_16x16x32_bf16(av, b1, acc[m][1], 0, 0, 0);
            }
        }
        __syncthreads();
    }

    float u0 = u[c0 + lrow], v0 = v[c0 + lrow];
    float u1 = u[c0 + 16 + lrow], v1 = v[c0 + 16 + lrow];
#pragma unroll
    for (int m = 0; m < 4; m++) {
#pragma unroll
        for (int jj = 0; jj < 4; jj++) {
            int orow = r0 + m * 16 + lk8 * 4 + jj;
            if (orow < N_NODES) {
                float mur = mu[orow], rsr = rstd[orow], dor = do_is[orow];
                out[(size_t)orow * HID + c0 + lrow] =
                    f2bf((rsr * (acc[m][0][jj] - mur * u0) + v0) * dor);
                out[(size_t)orow * HID + c0 + 16 + lrow] =
                    f2bf((rsr * (acc[m][1][jj] - mur * u1) + v1) * dor);
            }
        }
    }
}

// ---------------- GEMM2 + LN + ReLU + GEMM3 fused ----------------

__global__ void k_gemm23(const unsigned short* __restrict__ A,
                         const unsigned short* __restrict__ Wt1,
                         const unsigned short* __restrict__ Wt2,
                         const float* __restrict__ di_is, const float* __restrict__ do_is,
                         const float* __restrict__ g, const float* __restrict__ b,
                         unsigned short* __restrict__ hc) {
    __shared__ float tile[64 * LNS2];  // 33.8 KB
    int t = threadIdx.x;
    int w = t >> 6, l = t & 63;
    int r0 = blockIdx.x * 64;
    int c0 = w * 32;
    int lrow = l & 15, lk8 = l >> 4;

    // --- GEMM2 ---
    const short8* ap[4];
#pragma unroll
    for (int m = 0; m < 4; m++) {
        int row = r0 + m * 16 + lrow;
        if (row > N_NODES - 1) row = N_NODES - 1;
        ap[m] = (const short8*)(A + (size_t)row * HID) + lk8;
    }
    const short8* bp[2];
#pragma unroll
    for (int n = 0; n < 2; n++) {
        bp[n] = (const short8*)(Wt1 + (size_t)(c0 + n * 16 + lrow) * HID) + lk8;
    }
    f32x4 acc[4][2] = {};
#pragma unroll
    for (int k0 = 0; k0 < HID / 8; k0 += 4) {
        short8 bv0 = bp[0][k0];
        short8 bv1 = bp[1][k0];
#pragma unroll
        for (int m = 0; m < 4; m++) {
            short8 av = ap[m][k0];
            acc[m][0] = __builtin_amdgcn_mfma_f32_16x16x32_bf16(av, bv0, acc[m][0], 0, 0, 0);
            acc[m][1] = __builtin_amdgcn_mfma_f32_16x16x32_bf16(av, bv1, acc[m][1], 0, 0, 0);
        }
    }
#pragma unroll
    for (int m = 0; m < 4; m++) {
#pragma unroll
        for (int j = 0; j < 4; j++) {
            int rl = m * 16 + lk8 * 4 + j;
            int grow = r0 + rl;
            float sc = di_is[(grow < N_NODES) ? grow : (N_NODES - 1)];
            tile[rl * LNS2 + c0 + lrow] = acc[m][0][j] * sc;
            tile[rl * LNS2 + c0 + 16 + lrow] = acc[m][1][j] * sc;
        }
    }
    __syncthreads();

    // --- LN + ReLU + x do_is (read-all -> barrier -> packed overwrite) ---
    int r = w * 16 + lrow;
    int qq = lk8;
    float s1 = 0.f, s2 = 0.f;
#pragma unroll
    for (int c = 0; c < 32; c++) {
        int cs = (c + qq * 8) & 31;
        float v = tile[r * LNS2 + qq * 32 + cs];
        s1 += v;
        s2 += v * v;
    }
    s1 += __shfl_xor(s1, 16); s2 += __shfl_xor(s2, 16);
    s1 += __shfl_xor(s1, 32); s2 += __shfl_xor(s2, 32);
    float mu = s1 * (1.f / 128.f);
    float var = s2 * (1.f / 128.f) - mu * mu;
    float rstd = rsqrtf(var + EPS);
    int grow = r0 + r;
    float sc = do_is[(grow < N_NODES) ? grow : (N_NODES - 1)];

    float vv0[16], vv1[16];
#pragma unroll
    for (int cc = 0; cc < 16; cc++) {
        vv0[cc] = tile[r * LNS2 + qq * 32 + 2 * cc];
        vv1[cc] = tile[r * LNS2 + qq * 32 + 2 * cc + 1];
    }
    __syncthreads();

    unsigned* tu = (unsigned*)tile;
    const float2* g2 = (const float2*)(g + qq * 32);
    const float2* b2v = (const float2*)(b + qq * 32);
#pragma unroll
    for (int cc = 0; cc < 16; cc++) {
        float2 gg = g2[cc];
        float2 bb = b2v[cc];
        float y0 = fmaxf((vv0[cc] - mu) * rstd * gg.x + bb.x, 0.f) * sc;
        float y1 = fmaxf((vv1[cc] - mu) * rstd * gg.y + bb.y, 0.f) * sc;
        tu[r * LNS2 + qq * 16 + cc] = pack2bf(y0, y1);
    }
    __syncthreads();

    // --- GEMM3 ---
    const short8* bp2[3];
#pragma unroll
    for (int n = 0; n < 3; n++) {
        bp2[n] = (const short8*)(Wt2 + (size_t)(n * 16 + lrow) * HID) + lk8;
    }
    f32x4 a3[3] = {};
#pragma unroll
    for (int kf = 0; kf < 4; kf++) {
        short8 av = *(const short8*)(&tu[(w * 16 + lrow) * LNS2 + kf * 16 + lk8 * 4]);
#pragma unroll
        for (int n = 0; n < 3; n++) {
            a3[n] = __builtin_amdgcn_mfma_f32_16x16x32_bf16(av, bp2[n][kf * 4], a3[n], 0, 0, 0);
        }
    }
#pragma unroll
    for (int n = 0; n < 3; n++) {
        int colw = n * 16 + lrow;
#pragma unroll
        for (int j = 0; j < 4; j++) {
            int orow = r0 + w * 16 + lk8 * 4 + j;
            if (orow < N_NODES) hc[(size_t)orow * CSTRIDE + colw] = f2bf(a3[n][j]);
        }
    }
}

// ---------------- agg + LN + ReLU (layer 0): 16 lanes/node, uint4 gathers, idx prefetch ----------------

__global__ void k_aggln(const unsigned short* __restrict__ h, const int* __restrict__ start,
                        const int* __restrict__ deg, const int* __restrict__ col,
                        const float* __restrict__ di_is, const float* __restrict__ do_is,
                        const float* __restrict__ g, const float* __restrict__ b,
                        unsigned* __restrict__ out) {
    int grp = (blockIdx.x * blockDim.x + threadIdx.x) >> 4;
    int gl = threadIdx.x & 15;
    if (grp >= N_NODES) return;
    int s0 = start[grp], e0 = s0 + deg[grp];
    const uint4* h4 = (const uint4*)h;  // row = 16 uint4
    float a[8] = {};
    int n8 = (e0 - s0) >> 3;
    int idx[8];
    if (n8 > 0) {
#pragma unroll
        for (int k = 0; k < 8; k++) idx[k] = col[s0 + k];
    }
    for (int bq = 0; bq < n8; bq++) {
        uint4 u[8];
#pragma unroll
        for (int k = 0; k < 8; k++) u[k] = h4[(size_t)idx[k] * 16 + gl];
        if (bq + 1 < n8) {
            int base = s0 + (bq + 1) * 8;
#pragma unroll
            for (int k = 0; k < 8; k++) idx[k] = col[base + k];
        }
#pragma unroll
        for (int k = 0; k < 8; k++) acc8(a, u[k]);
    }
    for (int i = s0 + n8 * 8; i < e0; i++) acc8(a, h4[(size_t)col[i] * 16 + gl]);

    float di = di_is[grp];
#pragma unroll
    for (int j = 0; j < 8; j++) a[j] *= di;
    float s = 0.f, q = 0.f;
#pragma unroll
    for (int j = 0; j < 8; j++) { s += a[j]; q += a[j] * a[j]; }
#pragma unroll
    for (int m = 1; m < 16; m <<= 1) {
        s += __shfl_xor(s, m);
        q += __shfl_xor(q, m);
    }
    float mu = s * (1.f / 128.f);
    float var = q * (1.f / 128.f) - mu * mu;
    float rstd = rsqrtf(var + EPS);
    float sc = do_is[grp];
    const float4* g4 = (const float4*)(g + gl * 8);
    const float4* b4 = (const float4*)(b + gl * 8);
    float4 g0v = g4[0], g1v = g4[1];
    float4 b0v = b4[0], b1v = b4[1];
    uint4 o;
    o.x = pack2bf(fmaxf((a[0] - mu) * rstd * g0v.x + b0v.x, 0.f) * sc,
                  fmaxf((a[1] - mu) * rstd * g0v.y + b0v.y, 0.f) * sc);
    o.y = pack2bf(fmaxf((a[2] - mu) * rstd * g0v.z + b0v.z, 0.f) * sc,
                  fmaxf((a[3] - mu) * rstd * g0v.w + b0v.w, 0.f) * sc);
    o.z = pack2bf(fmaxf((a[4] - mu) * rstd * g1v.x + b1v.x, 0.f) * sc,
                  fmaxf((a[5] - mu) * rstd * g1v.y + b1v.y, 0.f) * sc);
    o.w = pack2bf(fmaxf((a[6] - mu) * rstd * g1v.z + b1v.z, 0.f) * sc,
                  fmaxf((a[7] - mu) * rstd * g1v.w + b1v.w, 0.f) * sc);
    ((uint4*)out)[(size_t)grp * 16 + gl] = o;
}

// ---------------- agg (layer 1): 16 lanes/node, uint4 gathers, idx prefetch ----------------

__global__ void k_agg128b(const unsigned short* __restrict__ h, const int* __restrict__ start,
                          const int* __restrict__ deg, const int* __restrict__ col,
                          unsigned* __restrict__ out) {
    int grp = (blockIdx.x * blockDim.x + threadIdx.x) >> 4;
    int gl = threadIdx.x & 15;
    if (grp >= N_NODES) return;
    int s0 = start[grp], e0 = s0 + deg[grp];
    const uint4* h4 = (const uint4*)h;
    float a[8] = {};
    int n8 = (e0 - s0) >> 3;
    int idx[8];
    if (n8 > 0) {
#pragma unroll
        for (int k = 0; k < 8; k++) idx[k] = col[s0 + k];
    }
    for (int bq = 0; bq < n8; bq++) {
        uint4 u[8];
#pragma unroll
        for (int k = 0; k < 8; k++) u[k] = h4[(size_t)idx[k] * 16 + gl];
        if (bq + 1 < n8) {
            int base = s0 + (bq + 1) * 8;
#pragma unroll
            for (int k = 0; k < 8; k++) idx[k] = col[base + k];
        }
#pragma unroll
        for (int k = 0; k < 8; k++) acc8(a, u[k]);
    }
    for (int i = s0 + n8 * 8; i < e0; i++) acc8(a, h4[(size_t)col[i] * 16 + gl]);

    uint4 o;
    o.x = pack2bf(a[0], a[1]);
    o.y = pack2bf(a[2], a[3]);
    o.z = pack2bf(a[4], a[5]);
    o.w = pack2bf(a[6], a[7]);
    ((uint4*)out)[(size_t)grp * 16 + gl] = o;
}

// ---------------- agg (layer 2): 16 lanes/node, uint2 gathers on padded rows, idx prefetch ----------------

__global__ void k_agg40b(const unsigned short* __restrict__ h, const int* __restrict__ start,
                         const int* __restrict__ deg, const int* __restrict__ col,
                         const float* __restrict__ di_is, const float* __restrict__ b2,
                         float* __restrict__ out) {
    int grp = (blockIdx.x * blockDim.x + threadIdx.x) >> 4;
    int gl = threadIdx.x & 15;
    if (grp >= N_NODES) return;
    int s0 = start[grp], e0 = s0 + deg[grp];
    const uint2* h2 = (const uint2*)h;  // padded row = 16 uint2 (128 B)
    float a[4] = {};
    int n8 = (e0 - s0) >> 3;
    int idx[8];
    if (n8 > 0) {
#pragma unroll
        for (int k = 0; k < 8; k++) idx[k] = col[s0 + k];
    }
    for (int bq = 0; bq < n8; bq++) {
        uint2 u[8];
#pragma unroll
        for (int k = 0; k < 8; k++) u[k] = h2[(size_t)idx[k] * 16 + gl];
        if (bq + 1 < n8) {
            int base = s0 + (bq + 1) * 8;
#pragma unroll
            for (int k = 0; k < 8; k++) idx[k] = col[base + k];
        }
#pragma unroll
        for (int k = 0; k < 8; k++) acc4(a, u[k]);
    }
    for (int i = s0 + n8 * 8; i < e0; i++) acc4(a, h2[(size_t)col[i] * 16 + gl]);

    if (gl < CLS / 4) {  // lanes 0..9 cover the 40 real channels
        float di = di_is[grp];
        float4 bb = *(const float4*)(b2 + gl * 4);
        float4 o;
        o.x = a[0] * di + bb.x;
        o.y = a[1] * di + bb.y;
        o.z = a[2] * di + bb.z;
        o.w = a[3] * di + bb.w;
        *(float4*)(out + (size_t)grp * CLS + gl * 4) = o;
    }
}

// ---------------- launch ----------------

extern "C" void kernel_launch(void* const* d_in, const int* in_sizes, int n_in,
                              void* d_out, int out_size, void* d_ws, size_t ws_size,
                              hipStream_t stream) {
    (void)in_sizes; (void)n_in; (void)out_size; (void)ws_size;
    const float* feat = (const float*)d_in[0];
    const int*   src  = (const int*)d_in[1];
    const int*   dst  = (const int*)d_in[2];
    const float* W0   = (const float*)d_in[3];
    const float* W1   = (const float*)d_in[4];
    const float* W2   = (const float*)d_in[5];
    const float* b2   = (const float*)d_in[6];
    const float* g_in = (const float*)d_in[7];
    const float* b_in = (const float*)d_in[8];
    const float* g0   = (const float*)d_in[9];
    const float* b0   = (const float*)d_in[10];
    const float* g1   = (const float*)d_in[11];
    const float* b1   = (const float*)d_in[12];
    float* out = (float*)d_out;

    char* w = (char*)d_ws;
    size_t off = 0;
    auto take = [&](size_t bytes) -> void* {
        void* p = w + off;
        off += (bytes + 255) & ~(size_t)255;
        return p;
    };
    // zeroed region: deg_out8[8][N] | deg_in8[8][N] | cnt | counter
    const size_t SZ8N = ((size_t)NSH * N_NODES * 4 + 255) & ~(size_t)255;
    const size_t SZN = ((size_t)N_NODES * 4 + 255) & ~(size_t)255;
    char* zblk      = (char*)take(2 * SZ8N + SZN + 256);
    int*  deg_out8  = (int*)zblk;
    int*  deg_in8   = (int*)(zblk + SZ8N);
    int*  cnt       = (int*)(zblk + 2 * SZ8N);
    int*  counter   = (int*)(zblk + 2 * SZ8N + SZN);

    int*   deg_in_s  = (int*)take((size_t)N_NODES * 4);
    float* do_is     = (float*)take((size_t)N_NODES * 4);
    float* di_is     = (float*)take((size_t)N_NODES * 4);
    int*   start     = (int*)take((size_t)N_NODES * 4);
    int*   col       = (int*)take((size_t)N_EDGES * 4);
    float* mu        = (float*)take((size_t)N_NODES * 4);
    float* rstd      = (float*)take((size_t)N_NODES * 4);
    float* uvec      = (float*)take((size_t)HID * 4);
    float* vvec      = (float*)take((size_t)HID * 4);
    unsigned short* Abf = (unsigned short*)take((size_t)(N_NODES + 64) * IN_F * 2);
    unsigned short* Wg  = (unsigned short*)take((size_t)IN_F * HID * 2);
    unsigned short* Wt1 = (unsigned short*)take((size_t)HID * HID * 2);
    unsigned short* Wt2 = (unsigned short*)take((size_t)HID * CLSP * 2);
    unsigned short* h0  = (unsigned short*)take((size_t)N_NODES * HID * 2);
    unsigned short* h1  = (unsigned short*)take((size_t)N_NODES * HID * 2);
    unsigned short* hb  = (unsigned short*)take((size_t)N_NODES * HID * 2);
    unsigned short* hc  = (unsigned short*)take((size_t)N_NODES * CSTRIDE * 2);

    const int NB_N = (N_NODES + 255) / 256;
    const int NB_E = (N_EDGES + 255) / 256;           // 3125
    const int NB_E4 = (N_EDGES / 4 + 255) / 256;      // 782 (int4 edge blocks, fill)
    const int NB_M64 = (N_NODES + 63) / 64;           // 782
    const int NB_G16 = (N_NODES * 16 + 255) / 256;    // 3125 (16 lanes per node)
    const int S3 = HID * HID + HID * CLSP + IN_F * HID;  // 120832
    const int NB_CVT = (S3 + 255) / 256;                 // 472

    hipMemsetAsync(zblk, 0, 2 * SZ8N + SZN + 256, stream);

    // atomics + cvtstat (1:1) with weight-prep tail blocks
    k_deg_cvt<<<NB_E + NB_G16 + NB_CVT + 32, 256, 0, stream>>>(
        src, dst, deg_out8, deg_in8, feat, Abf, mu, rstd,
        W0, W1, W2, g_in, b_in, Wg, Wt1, Wt2, uvec, vvec);
    // offsets (sums shadows)
    k_off<<<NB_N, 256, 0, stream>>>(deg_in8, deg_out8, deg_in_s, start, do_is, di_is, counter);

    // fused: even blocks = GEMM1 (LN folded), odd blocks = CSR fill (int4 edges)
    k_fill_gemm1<<<NB_E4 + NB_M64, 256, 0, stream>>>((const int4*)src, (const int4*)dst,
                                                     start, cnt, col, Abf, Wg, mu, rstd,
                                                     uvec, vvec, do_is, h0);

    // Layer 0 epilogue: h1 = relu(LN(agg(h0)*di_is))*do_is
    k_aggln<<<NB_G16, 256, 0, stream>>>(h0, start, deg_in_s, col, di_is, do_is, g0, b0, (unsigned*)h1);

    // Layer 1+2a: hb = agg(h1) ; hc = (relu(LN((hb@W1)*di_is))*do_is) @ W2
    k_agg128b<<<NB_G16, 256, 0, stream>>>(h1, start, deg_in_s, col, (unsigned*)hb);
    k_gemm23<<<NB_M64, 256, 0, stream>>>(hb, Wt1, Wt2, di_is, do_is, g1, b1, hc);

    // Layer 2b: out = agg(hc)*di_is + b2
    k_agg40b<<<NB_G16, 256, 0, stream>>>(hc, start, deg_in_s, col, di_is, b2, out);
}

// Round 20
// 275.770 us; speedup vs baseline: 1.3813x; 1.0070x over previous
//
#include <hip/hip_runtime.h>
#include <math.h>

#define N_NODES 50000
#define N_EDGES 800000
#define IN_F 768
#define HID 128
#define CLS 40
#define CLSP 48
#define CSTRIDE 64   // padded row stride (shorts) for hc
#define EPS 1e-5f
#define LNS2 132     // f32 LDS stride for gemm23 tile
#define BK1 64       // K-step for staged GEMM1
#define NSH 4        // degree histogram shadows

typedef __attribute__((ext_vector_type(8))) short short8;
typedef __attribute__((ext_vector_type(4))) float f32x4;

__device__ inline unsigned short f2bf(float f) {
    union { float f; unsigned u; } x;
    x.f = f;
    unsigned u = x.u;
    return (unsigned short)((u + 0x7FFF + ((u >> 16) & 1)) >> 16);
}

__device__ inline float bf2f(unsigned short u) {
    union { unsigned u; float f; } x;
    x.u = ((unsigned)u) << 16;
    return x.f;
}

__device__ inline unsigned pack2bf(float a, float b) {
    return (unsigned)f2bf(a) | ((unsigned)f2bf(b) << 16);
}

__device__ inline void acc8(float* a, uint4 u) {
    a[0] += bf2f((unsigned short)(u.x & 0xFFFF));
    a[1] += bf2f((unsigned short)(u.x >> 16));
    a[2] += bf2f((unsigned short)(u.y & 0xFFFF));
    a[3] += bf2f((unsigned short)(u.y >> 16));
    a[4] += bf2f((unsigned short)(u.z & 0xFFFF));
    a[5] += bf2f((unsigned short)(u.z >> 16));
    a[6] += bf2f((unsigned short)(u.w & 0xFFFF));
    a[7] += bf2f((unsigned short)(u.w >> 16));
}

__device__ inline void acc4(float* a, uint2 u) {
    a[0] += bf2f((unsigned short)(u.x & 0xFFFF));
    a[1] += bf2f((unsigned short)(u.x >> 16));
    a[2] += bf2f((unsigned short)(u.y & 0xFFFF));
    a[3] += bf2f((unsigned short)(u.y >> 16));
}

// ---------------- fused: degree atomics + feat cvt/stats + weight prep ----------------
// Blocks [0, 6250): 1:1 interleave of per-edge atomics (even) and 16-lane cvtstat (odd).
// Blocks [6250, +NB_CVT+32): weight prep tail (independent; rides free while main drains).

__global__ void k_deg_cvt(const int* __restrict__ src, const int* __restrict__ dst,
                          int* __restrict__ deg_out8, int* __restrict__ deg_in8,
                          const float* __restrict__ feat, unsigned short* __restrict__ Abf,
                          float* __restrict__ mu_o, float* __restrict__ rstd_o,
                          const float* __restrict__ W0, const float* __restrict__ W1,
                          const float* __restrict__ W2, const float* __restrict__ g_in,
                          const float* __restrict__ b_in,
                          unsigned short* __restrict__ Wg, unsigned short* __restrict__ Wt1,
                          unsigned short* __restrict__ Wt2,
                          float* __restrict__ u, float* __restrict__ v) {
    const int NB_E = (N_EDGES + 255) / 256;        // 3125
    const int NB_G16 = (N_NODES * 16 + 255) / 256; // 3125
    const int MAIN = NB_E + NB_G16;                // 6250
    const int S1 = HID * HID;
    const int S2 = S1 + HID * CLSP;
    const int S3 = S2 + IN_F * HID;
    const int NB_CVT = (S3 + 255) / 256;           // 472

    if ((int)blockIdx.x < MAIN) {
        int half = (int)blockIdx.x >> 1;
        if ((blockIdx.x & 1) == 0) {
            int e = half * 256 + (int)threadIdx.x;
            if (e < N_EDGES) {
                int sh = half & (NSH - 1);
                atomicAdd(&deg_out8[(size_t)sh * N_NODES + src[e]], 1);
                atomicAdd(&deg_in8[(size_t)sh * N_NODES + dst[e]], 1);
            }
            return;
        }
        // cvtstat: 16 lanes per row
        int grp = (half * 256 + (int)threadIdx.x) >> 4;
        int gl = threadIdx.x & 15;
        if (grp >= N_NODES) return;
        const float4* x4 = (const float4*)(feat + (size_t)grp * IN_F);
        float4 vv[12];
#pragma unroll
        for (int j = 0; j < 12; j++) vv[j] = x4[gl + 16 * j];
        float s = 0.f, q = 0.f;
#pragma unroll
        for (int j = 0; j < 12; j++) {
            float4 tv = vv[j];
            s += tv.x + tv.y + tv.z + tv.w;
            q += tv.x * tv.x + tv.y * tv.y + tv.z * tv.z + tv.w * tv.w;
        }
#pragma unroll
        for (int m = 1; m < 16; m <<= 1) {
            s += __shfl_xor(s, m);
            q += __shfl_xor(q, m);
        }
        float mu = s * (1.f / (float)IN_F);
        float var = q * (1.f / (float)IN_F) - mu * mu;
        float rstd = rsqrtf(var + EPS);
        ushort4* orow = (ushort4*)(Abf + (size_t)grp * IN_F);
#pragma unroll
        for (int j = 0; j < 12; j++) {
            ushort4 o;
            o.x = f2bf(vv[j].x); o.y = f2bf(vv[j].y);
            o.z = f2bf(vv[j].z); o.w = f2bf(vv[j].w);
            orow[gl + 16 * j] = o;
        }
        if (gl == 0) {
            mu_o[grp] = mu;
            rstd_o[grp] = rstd;
        }
        return;
    }
    // ---- weight prep tail ----
    int cb = (int)blockIdx.x - MAIN;
    if (cb < NB_CVT) {
        int idx = cb * 256 + threadIdx.x;
        if (idx < S1) {
            int c = idx / HID, k = idx % HID;
            Wt1[idx] = f2bf(W1[(size_t)k * HID + c]);
        } else if (idx < S2) {
            int j = idx - S1;
            int c = j / HID, k = j % HID;
            Wt2[j] = (c < CLS) ? f2bf(W2[(size_t)k * CLS + c]) : (unsigned short)0;
        } else if (idx < S3) {
            int j = idx - S2;
            int c = j / IN_F, k = j % IN_F;
            Wg[j] = f2bf(g_in[k] * W0[(size_t)k * HID + c]);
        }
    } else {
        int wvid = (cb - NB_CVT) * 4 + (threadIdx.x >> 6);
        int lane = threadIdx.x & 63;
        if (wvid < HID) {
            float us = 0.f, vs = 0.f;
#pragma unroll
            for (int i = 0; i < 12; i++) {
                int k = lane + 64 * i;
                float w0 = W0[(size_t)k * HID + wvid];
                us += bf2f(f2bf(g_in[k] * w0));  // match bf16-rounded Wg exactly
                vs += b_in[k] * w0;
            }
#pragma unroll
            for (int m = 1; m < 64; m <<= 1) {
                us += __shfl_xor(us, m);
                vs += __shfl_xor(vs, m);
            }
            if (lane == 0) { u[wvid] = us; v[wvid] = vs; }
        }
    }
}

// ---------------- segment offsets (sums shadows) ----------------

__global__ void k_off(const int* __restrict__ deg_in8, const int* __restrict__ deg_out8,
                      int* __restrict__ deg_in_s, int* __restrict__ start,
                      float* __restrict__ do_is, float* __restrict__ di_is,
                      int* __restrict__ counter) {
    int i = blockIdx.x * 256 + threadIdx.x;
    int lane = threadIdx.x & 63;
    int d = 0, dout = 0;
    if (i < N_NODES) {
#pragma unroll
        for (int sh = 0; sh < NSH; sh++) {
            d += deg_in8[(size_t)sh * N_NODES + i];
            dout += deg_out8[(size_t)sh * N_NODES + i];
        }
    }
    int pre = d;
#pragma unroll
    for (int m = 1; m < 64; m <<= 1) {
        int vv = __shfl_up(pre, m);
        if (lane >= m) pre += vv;
    }
    int total = __shfl(pre, 63);
    int base = 0;
    if (lane == 63) base = atomicAdd(counter, total);
    base = __shfl(base, 63);
    if (i < N_NODES) {
        deg_in_s[i] = d;
        start[i] = base + pre - d;
        di_is[i] = rsqrtf((float)max(d, 1));
        do_is[i] = rsqrtf((float)max(dout, 1));
    }
}

// ---------------- fused: CSR fill (int4 edges) + GEMM1 staged ----------------

__global__ __launch_bounds__(256) void k_fill_gemm1(
        const int4* __restrict__ src4, const int4* __restrict__ dst4,
        const int* __restrict__ start, int* __restrict__ cnt, int* __restrict__ col,
        const unsigned short* __restrict__ Abf, const unsigned short* __restrict__ Wg,
        const float* __restrict__ mu, const float* __restrict__ rstd,
        const float* __restrict__ u, const float* __restrict__ v,
        const float* __restrict__ do_is, unsigned short* __restrict__ out) {
    __shared__ unsigned short As[2][8][64][8];  // 2 x 8 KB (gemm path only)
    if (blockIdx.x & 1) {
        // ---- CSR fill, 4 edges per thread ----
        int half = (int)blockIdx.x >> 1;
        int idx4 = half * 256 + (int)threadIdx.x;
        if (idx4 < N_EDGES / 4) {
            int4 s4 = src4[idx4];
            int4 d4 = dst4[idx4];
            int p0 = start[d4.x] + atomicAdd(&cnt[d4.x], 1);
            col[p0] = s4.x;
            int p1 = start[d4.y] + atomicAdd(&cnt[d4.y], 1);
            col[p1] = s4.y;
            int p2 = start[d4.z] + atomicAdd(&cnt[d4.z], 1);
            col[p2] = s4.z;
            int p3 = start[d4.w] + atomicAdd(&cnt[d4.w], 1);
            col[p3] = s4.w;
        }
        return;
    }
    // ---- GEMM1 staged ----
    int bid = (int)blockIdx.x >> 1;
    int t = threadIdx.x;
    int w = t >> 6, l = t & 63;
    int r0 = bid * 64;
    int c0 = w * 32;
    int lrow = l & 15, lk8 = l >> 4;

    const unsigned short* srow = Abf + (size_t)(r0 + l) * IN_F;  // per-lane source row

    const short8* bp0 = (const short8*)(Wg + (size_t)(c0 + lrow) * IN_F);
    const short8* bp1 = (const short8*)(Wg + (size_t)(c0 + 16 + lrow) * IN_F);

    f32x4 acc[4][2] = {};

#define STAGE1(bsel, s)                                                          \
    {                                                                            \
        _Pragma("unroll")                                                        \
        for (int i = 0; i < 2; i++) {                                            \
            int k8 = w * 2 + i;                                                  \
            __builtin_amdgcn_global_load_lds(                                    \
                (const __attribute__((address_space(1))) void*)(srow + (s)*BK1 + k8 * 8), \
                (__attribute__((address_space(3))) void*)(&As[bsel][k8][0][0]),  \
                16, 0, 0);                                                       \
        }                                                                        \
    }

    STAGE1(0, 0);
    __syncthreads();

#pragma unroll 1
    for (int s = 0; s < IN_F / BK1; s++) {
        int cur = s & 1;
        if (s + 1 < IN_F / BK1) STAGE1(cur ^ 1, s + 1);
#pragma unroll
        for (int j = 0; j < 2; j++) {
            short8 b0 = bp0[s * 8 + j * 4 + lk8];
            short8 b1 = bp1[s * 8 + j * 4 + lk8];
#pragma unroll
            for (int m = 0; m < 4; m++) {
                short8 av = *(const short8*)(&As[cur][j * 4 + lk8][m * 16 + lrow][0]);
                acc[m][0] = __builtin_amdgcn_mfma_f32_16x16x32_bf16(av, b0, acc[m][0], 0, 0, 0);
                acc[m][1] = __builtin_amdgcn_mfma_f32_16x16x32_bf16(av, b1, acc[m][1], 0, 0, 0);
            }
        }
        __syncthreads();
    }

    float u0 = u[c0 + lrow], v0 = v[c0 + lrow];
    float u1 = u[c0 + 16 + lrow], v1 = v[c0 + 16 + lrow];
#pragma unroll
    for (int m = 0; m < 4; m++) {
#pragma unroll
        for (int jj = 0; jj < 4; jj++) {
            int orow = r0 + m * 16 + lk8 * 4 + jj;
            if (orow < N_NODES) {
                float mur = mu[orow], rsr = rstd[orow], dor = do_is[orow];
                out[(size_t)orow * HID + c0 + lrow] =
                    f2bf((rsr * (acc[m][0][jj] - mur * u0) + v0) * dor);
                out[(size_t)orow * HID + c0 + 16 + lrow] =
                    f2bf((rsr * (acc[m][1][jj] - mur * u1) + v1) * dor);
            }
        }
    }
}

// ---------------- GEMM2 + LN + ReLU + GEMM3 fused ----------------

__global__ void k_gemm23(const unsigned short* __restrict__ A,
                         const unsigned short* __restrict__ Wt1,
                         const unsigned short* __restrict__ Wt2,
                         const float* __restrict__ di_is, const float* __restrict__ do_is,
                         const float* __restrict__ g, const float* __restrict__ b,
                         unsigned short* __restrict__ hc) {
    __shared__ float tile[64 * LNS2];  // 33.8 KB
    int t = threadIdx.x;
    int w = t >> 6, l = t & 63;
    int r0 = blockIdx.x * 64;
    int c0 = w * 32;
    int lrow = l & 15, lk8 = l >> 4;

    // --- GEMM2 ---
    const short8* ap[4];
#pragma unroll
    for (int m = 0; m < 4; m++) {
        int row = r0 + m * 16 + lrow;
        if (row > N_NODES - 1) row = N_NODES - 1;
        ap[m] = (const short8*)(A + (size_t)row * HID) + lk8;
    }
    const short8* bp[2];
#pragma unroll
    for (int n = 0; n < 2; n++) {
        bp[n] = (const short8*)(Wt1 + (size_t)(c0 + n * 16 + lrow) * HID) + lk8;
    }
    f32x4 acc[4][2] = {};
#pragma unroll
    for (int k0 = 0; k0 < HID / 8; k0 += 4) {
        short8 bv0 = bp[0][k0];
        short8 bv1 = bp[1][k0];
#pragma unroll
        for (int m = 0; m < 4; m++) {
            short8 av = ap[m][k0];
            acc[m][0] = __builtin_amdgcn_mfma_f32_16x16x32_bf16(av, bv0, acc[m][0], 0, 0, 0);
            acc[m][1] = __builtin_amdgcn_mfma_f32_16x16x32_bf16(av, bv1, acc[m][1], 0, 0, 0);
        }
    }
#pragma unroll
    for (int m = 0; m < 4; m++) {
#pragma unroll
        for (int j = 0; j < 4; j++) {
            int rl = m * 16 + lk8 * 4 + j;
            int grow = r0 + rl;
            float sc = di_is[(grow < N_NODES) ? grow : (N_NODES - 1)];
            tile[rl * LNS2 + c0 + lrow] = acc[m][0][j] * sc;
            tile[rl * LNS2 + c0 + 16 + lrow] = acc[m][1][j] * sc;
        }
    }
    __syncthreads();

    // --- LN + ReLU + x do_is (read-all -> barrier -> packed overwrite) ---
    int r = w * 16 + lrow;
    int qq = lk8;
    float s1 = 0.f, s2 = 0.f;
#pragma unroll
    for (int c = 0; c < 32; c++) {
        int cs = (c + qq * 8) & 31;
        float v = tile[r * LNS2 + qq * 32 + cs];
        s1 += v;
        s2 += v * v;
    }
    s1 += __shfl_xor(s1, 16); s2 += __shfl_xor(s2, 16);
    s1 += __shfl_xor(s1, 32); s2 += __shfl_xor(s2, 32);
    float mu = s1 * (1.f / 128.f);
    float var = s2 * (1.f / 128.f) - mu * mu;
    float rstd = rsqrtf(var + EPS);
    int grow = r0 + r;
    float sc = do_is[(grow < N_NODES) ? grow : (N_NODES - 1)];

    float vv0[16], vv1[16];
#pragma unroll
    for (int cc = 0; cc < 16; cc++) {
        vv0[cc] = tile[r * LNS2 + qq * 32 + 2 * cc];
        vv1[cc] = tile[r * LNS2 + qq * 32 + 2 * cc + 1];
    }
    __syncthreads();

    unsigned* tu = (unsigned*)tile;
    const float2* g2 = (const float2*)(g + qq * 32);
    const float2* b2v = (const float2*)(b + qq * 32);
#pragma unroll
    for (int cc = 0; cc < 16; cc++) {
        float2 gg = g2[cc];
        float2 bb = b2v[cc];
        float y0 = fmaxf((vv0[cc] - mu) * rstd * gg.x + bb.x, 0.f) * sc;
        float y1 = fmaxf((vv1[cc] - mu) * rstd * gg.y + bb.y, 0.f) * sc;
        tu[r * LNS2 + qq * 16 + cc] = pack2bf(y0, y1);
    }
    __syncthreads();

    // --- GEMM3 ---
    const short8* bp2[3];
#pragma unroll
    for (int n = 0; n < 3; n++) {
        bp2[n] = (const short8*)(Wt2 + (size_t)(n * 16 + lrow) * HID) + lk8;
    }
    f32x4 a3[3] = {};
#pragma unroll
    for (int kf = 0; kf < 4; kf++) {
        short8 av = *(const short8*)(&tu[(w * 16 + lrow) * LNS2 + kf * 16 + lk8 * 4]);
#pragma unroll
        for (int n = 0; n < 3; n++) {
            a3[n] = __builtin_amdgcn_mfma_f32_16x16x32_bf16(av, bp2[n][kf * 4], a3[n], 0, 0, 0);
        }
    }
#pragma unroll
    for (int n = 0; n < 3; n++) {
        int colw = n * 16 + lrow;
#pragma unroll
        for (int j = 0; j < 4; j++) {
            int orow = r0 + w * 16 + lk8 * 4 + j;
            if (orow < N_NODES) hc[(size_t)orow * CSTRIDE + colw] = f2bf(a3[n][j]);
        }
    }
}

// ---------------- agg + LN + ReLU (layer 0): 16 lanes/node, uint4 gathers, idx prefetch ----------------

__global__ void k_aggln(const unsigned short* __restrict__ h, const int* __restrict__ start,
                        const int* __restrict__ deg, const int* __restrict__ col,
                        const float* __restrict__ di_is, const float* __restrict__ do_is,
                        const float* __restrict__ g, const float* __restrict__ b,
                        unsigned* __restrict__ out) {
    int grp = (blockIdx.x * blockDim.x + threadIdx.x) >> 4;
    int gl = threadIdx.x & 15;
    if (grp >= N_NODES) return;
    int s0 = start[grp], e0 = s0 + deg[grp];
    const uint4* h4 = (const uint4*)h;  // row = 16 uint4
    float a[8] = {};
    int n8 = (e0 - s0) >> 3;
    int idx[8];
    if (n8 > 0) {
#pragma unroll
        for (int k = 0; k < 8; k++) idx[k] = col[s0 + k];
    }
    for (int bq = 0; bq < n8; bq++) {
        uint4 u[8];
#pragma unroll
        for (int k = 0; k < 8; k++) u[k] = h4[(size_t)idx[k] * 16 + gl];
        if (bq + 1 < n8) {
            int base = s0 + (bq + 1) * 8;
#pragma unroll
            for (int k = 0; k < 8; k++) idx[k] = col[base + k];
        }
#pragma unroll
        for (int k = 0; k < 8; k++) acc8(a, u[k]);
    }
    for (int i = s0 + n8 * 8; i < e0; i++) acc8(a, h4[(size_t)col[i] * 16 + gl]);

    float di = di_is[grp];
#pragma unroll
    for (int j = 0; j < 8; j++) a[j] *= di;
    float s = 0.f, q = 0.f;
#pragma unroll
    for (int j = 0; j < 8; j++) { s += a[j]; q += a[j] * a[j]; }
#pragma unroll
    for (int m = 1; m < 16; m <<= 1) {
        s += __shfl_xor(s, m);
        q += __shfl_xor(q, m);
    }
    float mu = s * (1.f / 128.f);
    float var = q * (1.f / 128.f) - mu * mu;
    float rstd = rsqrtf(var + EPS);
    float sc = do_is[grp];
    const float4* g4 = (const float4*)(g + gl * 8);
    const float4* b4 = (const float4*)(b + gl * 8);
    float4 g0v = g4[0], g1v = g4[1];
    float4 b0v = b4[0], b1v = b4[1];
    uint4 o;
    o.x = pack2bf(fmaxf((a[0] - mu) * rstd * g0v.x + b0v.x, 0.f) * sc,
                  fmaxf((a[1] - mu) * rstd * g0v.y + b0v.y, 0.f) * sc);
    o.y = pack2bf(fmaxf((a[2] - mu) * rstd * g0v.z + b0v.z, 0.f) * sc,
                  fmaxf((a[3] - mu) * rstd * g0v.w + b0v.w, 0.f) * sc);
    o.z = pack2bf(fmaxf((a[4] - mu) * rstd * g1v.x + b1v.x, 0.f) * sc,
                  fmaxf((a[5] - mu) * rstd * g1v.y + b1v.y, 0.f) * sc);
    o.w = pack2bf(fmaxf((a[6] - mu) * rstd * g1v.z + b1v.z, 0.f) * sc,
                  fmaxf((a[7] - mu) * rstd * g1v.w + b1v.w, 0.f) * sc);
    ((uint4*)out)[(size_t)grp * 16 + gl] = o;
}

// ---------------- agg (layer 1): 16 lanes/node, uint4 gathers, idx prefetch ----------------

__global__ void k_agg128b(const unsigned short* __restrict__ h, const int* __restrict__ start,
                          const int* __restrict__ deg, const int* __restrict__ col,
                          unsigned* __restrict__ out) {
    int grp = (blockIdx.x * blockDim.x + threadIdx.x) >> 4;
    int gl = threadIdx.x & 15;
    if (grp >= N_NODES) return;
    int s0 = start[grp], e0 = s0 + deg[grp];
    const uint4* h4 = (const uint4*)h;
    float a[8] = {};
    int n8 = (e0 - s0) >> 3;
    int idx[8];
    if (n8 > 0) {
#pragma unroll
        for (int k = 0; k < 8; k++) idx[k] = col[s0 + k];
    }
    for (int bq = 0; bq < n8; bq++) {
        uint4 u[8];
#pragma unroll
        for (int k = 0; k < 8; k++) u[k] = h4[(size_t)idx[k] * 16 + gl];
        if (bq + 1 < n8) {
            int base = s0 + (bq + 1) * 8;
#pragma unroll
            for (int k = 0; k < 8; k++) idx[k] = col[base + k];
        }
#pragma unroll
        for (int k = 0; k < 8; k++) acc8(a, u[k]);
    }
    for (int i = s0 + n8 * 8; i < e0; i++) acc8(a, h4[(size_t)col[i] * 16 + gl]);

    uint4 o;
    o.x = pack2bf(a[0], a[1]);
    o.y = pack2bf(a[2], a[3]);
    o.z = pack2bf(a[4], a[5]);
    o.w = pack2bf(a[6], a[7]);
    ((uint4*)out)[(size_t)grp * 16 + gl] = o;
}

// ---------------- agg (layer 2): 16 lanes/node, uint2 gathers on padded rows, idx prefetch ----------------

__global__ void k_agg40b(const unsigned short* __restrict__ h, const int* __restrict__ start,
                         const int* __restrict__ deg, const int* __restrict__ col,
                         const float* __restrict__ di_is, const float* __restrict__ b2,
                         float* __restrict__ out) {
    int grp = (blockIdx.x * blockDim.x + threadIdx.x) >> 4;
    int gl = threadIdx.x & 15;
    if (grp >= N_NODES) return;
    int s0 = start[grp], e0 = s0 + deg[grp];
    const uint2* h2 = (const uint2*)h;  // padded row = 16 uint2 (128 B)
    float a[4] = {};
    int n8 = (e0 - s0) >> 3;
    int idx[8];
    if (n8 > 0) {
#pragma unroll
        for (int k = 0; k < 8; k++) idx[k] = col[s0 + k];
    }
    for (int bq = 0; bq < n8; bq++) {
        uint2 u[8];
#pragma unroll
        for (int k = 0; k < 8; k++) u[k] = h2[(size_t)idx[k] * 16 + gl];
        if (bq + 1 < n8) {
            int base = s0 + (bq + 1) * 8;
#pragma unroll
            for (int k = 0; k < 8; k++) idx[k] = col[base + k];
        }
#pragma unroll
        for (int k = 0; k < 8; k++) acc4(a, u[k]);
    }
    for (int i = s0 + n8 * 8; i < e0; i++) acc4(a, h2[(size_t)col[i] * 16 + gl]);

    if (gl < CLS / 4) {  // lanes 0..9 cover the 40 real channels
        float di = di_is[grp];
        float4 bb = *(const float4*)(b2 + gl * 4);
        float4 o;
        o.x = a[0] * di + bb.x;
        o.y = a[1] * di + bb.y;
        o.z = a[2] * di + bb.z;
        o.w = a[3] * di + bb.w;
        *(float4*)(out + (size_t)grp * CLS + gl * 4) = o;
    }
}

// ---------------- launch ----------------

extern "C" void kernel_launch(void* const* d_in, const int* in_sizes, int n_in,
                              void* d_out, int out_size, void* d_ws, size_t ws_size,
                              hipStream_t stream) {
    (void)in_sizes; (void)n_in; (void)out_size; (void)ws_size;
    const float* feat = (const float*)d_in[0];
    const int*   src  = (const int*)d_in[1];
    const int*   dst  = (const int*)d_in[2];
    const float* W0   = (const float*)d_in[3];
    const float* W1   = (const float*)d_in[4];
    const float* W2   = (const float*)d_in[5];
    const float* b2   = (const float*)d_in[6];
    const float* g_in = (const float*)d_in[7];
    const float* b_in = (const float*)d_in[8];
    const float* g0   = (const float*)d_in[9];
    const float* b0   = (const float*)d_in[10];
    const float* g1   = (const float*)d_in[11];
    const float* b1   = (const float*)d_in[12];
    float* out = (float*)d_out;

    char* w = (char*)d_ws;
    size_t off = 0;
    auto take = [&](size_t bytes) -> void* {
        void* p = w + off;
        off += (bytes + 255) & ~(size_t)255;
        return p;
    };
    // zeroed region: deg_out8[NSH][N] | deg_in8[NSH][N] | cnt | counter
    const size_t SZSH = ((size_t)NSH * N_NODES * 4 + 255) & ~(size_t)255;
    const size_t SZN = ((size_t)N_NODES * 4 + 255) & ~(size_t)255;
    char* zblk      = (char*)take(2 * SZSH + SZN + 256);
    int*  deg_out8  = (int*)zblk;
    int*  deg_in8   = (int*)(zblk + SZSH);
    int*  cnt       = (int*)(zblk + 2 * SZSH);
    int*  counter   = (int*)(zblk + 2 * SZSH + SZN);

    int*   deg_in_s  = (int*)take((size_t)N_NODES * 4);
    float* do_is     = (float*)take((size_t)N_NODES * 4);
    float* di_is     = (float*)take((size_t)N_NODES * 4);
    int*   start     = (int*)take((size_t)N_NODES * 4);
    int*   col       = (int*)take((size_t)N_EDGES * 4);
    float* mu        = (float*)take((size_t)N_NODES * 4);
    float* rstd      = (float*)take((size_t)N_NODES * 4);
    float* uvec      = (float*)take((size_t)HID * 4);
    float* vvec      = (float*)take((size_t)HID * 4);
    unsigned short* Abf = (unsigned short*)take((size_t)(N_NODES + 64) * IN_F * 2);
    unsigned short* Wg  = (unsigned short*)take((size_t)IN_F * HID * 2);
    unsigned short* Wt1 = (unsigned short*)take((size_t)HID * HID * 2);
    unsigned short* Wt2 = (unsigned short*)take((size_t)HID * CLSP * 2);
    unsigned short* h0  = (unsigned short*)take((size_t)N_NODES * HID * 2);
    unsigned short* h1  = (unsigned short*)take((size_t)N_NODES * HID * 2);
    unsigned short* hb  = (unsigned short*)take((size_t)N_NODES * HID * 2);
    unsigned short* hc  = (unsigned short*)take((size_t)N_NODES * CSTRIDE * 2);

    const int NB_N = (N_NODES + 255) / 256;
    const int NB_E = (N_EDGES + 255) / 256;           // 3125
    const int NB_E4 = (N_EDGES / 4 + 255) / 256;      // 782 (int4 edge blocks, fill)
    const int NB_M64 = (N_NODES + 63) / 64;           // 782
    const int NB_G16 = (N_NODES * 16 + 255) / 256;    // 3125 (16 lanes per node)
    const int S3 = HID * HID + HID * CLSP + IN_F * HID;  // 120832
    const int NB_CVT = (S3 + 255) / 256;                 // 472

    hipMemsetAsync(zblk, 0, 2 * SZSH + SZN + 256, stream);

    // atomics + cvtstat (1:1) with weight-prep tail blocks
    k_deg_cvt<<<NB_E + NB_G16 + NB_CVT + 32, 256, 0, stream>>>(
        src, dst, deg_out8, deg_in8, feat, Abf, mu, rstd,
        W0, W1, W2, g_in, b_in, Wg, Wt1, Wt2, uvec, vvec);
    // offsets (sums shadows)
    k_off<<<NB_N, 256, 0, stream>>>(deg_in8, deg_out8, deg_in_s, start, do_is, di_is, counter);

    // fused: even blocks = GEMM1 (LN folded), odd blocks = CSR fill (int4 edges)
    k_fill_gemm1<<<NB_E4 + NB_M64, 256, 0, stream>>>((const int4*)src, (const int4*)dst,
                                                     start, cnt, col, Abf, Wg, mu, rstd,
                                                     uvec, vvec, do_is, h0);

    // Layer 0 epilogue: h1 = relu(LN(agg(h0)*di_is))*do_is
    k_aggln<<<NB_G16, 256, 0, stream>>>(h0, start, deg_in_s, col, di_is, do_is, g0, b0, (unsigned*)h1);

    // Layer 1+2a: hb = agg(h1) ; hc = (relu(LN((hb@W1)*di_is))*do_is) @ W2
    k_agg128b<<<NB_G16, 256, 0, stream>>>(h1, start, deg_in_s, col, (unsigned*)hb);
    k_gemm23<<<NB_M64, 256, 0, stream>>>(hb, Wt1, Wt2, di_is, do_is, g1, b1, hc);

    // Layer 2b: out = agg(hc)*di_is + b2
    k_agg40b<<<NB_G16, 256, 0, stream>>>(hc, start, deg_in_s, col, di_is, b2, out);
}